// Round 13
// baseline (628.919 us; speedup 1.0000x reference)
//
#include <hip/hip_runtime.h>

#define TSTEPS 8192
#define HDIM 4096
#define PDIM 4
#define KDIM 64

typedef unsigned short u16;
typedef __attribute__((ext_vector_type(8))) short short8;
typedef __attribute__((ext_vector_type(4))) float f32x4;

#define S1 -1.44269504089f   // -log2(e)
#define S2 -2.88539008177f   // -2*log2(e)

#if __has_builtin(__builtin_amdgcn_exp2f)
#define EXP2(x) __builtin_amdgcn_exp2f(x)
#else
#define EXP2(x) exp2f(x)
#endif
__device__ __forceinline__ float rcpf(float x) { return __builtin_amdgcn_rcpf(x); }

// tanh(c)*sig(o) for c in (-1,1), given ec = e^-o. Pade CF-7 tanh (err ~5e-6)
// merged into sig's rcp (r10 form -- best measured for L0 epilogue).
__device__ __forceinline__ float h_merge(float c, float ec) {
  float c2 = c * c;
  float num = c * fmaf(c2, 10.0f, 105.0f);
  float den = fmaf(c2, 45.0f, 105.0f) + c2 * c2;
  return num * rcpf(den * (1.0f + ec));
}

// Polynomial sig/tanh for SMALL-LAYER gates only (|z| <= ~0.6, 5-sigma; poly
// valid to |z|~1 at ~2e-5 err).
__device__ __forceinline__ float sig_poly(float z) {
  float z2 = z * z;
  float q = fmaf(z2, -2.1081349e-4f, 2.0833333e-3f);   // -17/80640, 1/480
  q = fmaf(z2, q, -2.0833333e-2f);                     // -1/48
  q = fmaf(z2, q, 0.25f);                              // 1/4
  return fmaf(z, q, 0.5f);
}
__device__ __forceinline__ float tanh_poly(float z) {
  float z2 = z * z;
  float q = fmaf(z2, -5.3968254e-2f, 1.3333333e-1f);   // -17/315, 2/15
  q = fmaf(z2, q, -3.3333333e-1f);                     // -1/3
  q = fmaf(z2, q, 1.0f);
  return z * q;
}

// async global->LDS DMA, 16B per lane; LDS dest = uniform base + lane*16
__device__ __forceinline__ void gload16(const void* g, void* l) {
  __builtin_amdgcn_global_load_lds((const __attribute__((address_space(1))) unsigned int*)g,
                                   (__attribute__((address_space(3))) unsigned int*)l,
                                   16, 0, 0);
}

__device__ __forceinline__ u16 bf16_rne(float f) {
  unsigned u = __float_as_uint(f);
  u += 0x7FFF + ((u >> 16) & 1);
  return (u16)(u >> 16);
}
__device__ __forceinline__ void hilo(float v, u16& h, u16& l) {
  h = bf16_rne(v);
  l = bf16_rne(v - __uint_as_float((unsigned)h << 16));
}

// ---- workspace layout (float offsets) ----
#define WS_Y0   0
#define WS_Y1   32768
#define WS_BSC  65536
#define WS_C1   77824
#define WS_C2   159744
#define WS_XHI  241664
#define WS_XLO  503808
#define WS_WHI  765952
#define WS_WLO  1159168
#define WS_PP   1552384
#define WS_BP   3649536
// bp (r21 layout, GATE-CONTIGUOUS): [L][tile][gate][lane][8 u16] -- the 3
// gate frags of one tile are 1KB apart so fused2 reads them from ONE base
// pointer with immediate offsets 0/1024/2048B. 786432 u16 total as before.

// One-shot prep (r24: back to a SINGLE launch -- the r23 double-launch probe
// measured prep's warm incremental cost at ~1-2us, i.e. roofline; the ~60us
// of unaccounted wall time is harness-fixed overhead, not prep).
__global__ void prep_kernel(const float* __restrict__ x,
                            const float* __restrict__ Wih0, const float* __restrict__ bih0,
                            const float* __restrict__ bhh0,
                            const float* __restrict__ Wih1, const float* __restrict__ bih1,
                            const float* __restrict__ bhh1, const float* __restrict__ Whr1,
                            const float* __restrict__ Wih2, const float* __restrict__ bih2,
                            const float* __restrict__ bhh2, const float* __restrict__ Whr2,
                            float* __restrict__ ws) {
  const int i = blockIdx.x * 256 + threadIdx.x;
  u16* xhi = (u16*)(ws + WS_XHI);
  u16* xlo = (u16*)(ws + WS_XLO);
  u16* whi = (u16*)(ws + WS_WHI);
  u16* wlo = (u16*)(ws + WS_WLO);

  if (i < 131072) {                       // x: 131072 float4 units, unscaled
    float4 v = *(const float4*)&x[i * 4];
    float val[4] = {v.x, v.y, v.z, v.w};
    u16 h[4], l[4];
#pragma unroll
    for (int e = 0; e < 4; ++e) hilo(val[e], h[e], l[e]);
    *(ushort4*)&xhi[i * 4] = make_ushort4(h[0], h[1], h[2], h[3]);
    *(ushort4*)&xlo[i * 4] = make_ushort4(l[0], l[1], l[2], l[3]);
  } else if (i < 327680) {                // W_ih0: 196608 float4 units, scaled
    int f = i - 131072;
    int el4 = f * 4;
    int r = el4 >> 6;                     // packed row 0..12287 ([gate][j])
    int k4 = el4 & 63;
    int gate = r >> 12, jr = r & 4095;
    int src = (gate == 0) ? jr : (gate + 1) * HDIM + jr;   // i,g,o = rows 0,2H,3H
    float sc = (gate == 1) ? S2 : S1;
    float4 v = *(const float4*)&Wih0[(size_t)src * KDIM + k4];
    float val[4] = {sc * v.x, sc * v.y, sc * v.z, sc * v.w};
    u16 h[4], l[4];
#pragma unroll
    for (int e = 0; e < 4; ++e) hilo(val[e], h[e], l[e]);
    *(ushort4*)&whi[r * KDIM + k4] = make_ushort4(h[0], h[1], h[2], h[3]);
    *(ushort4*)&wlo[r * KDIM + k4] = make_ushort4(l[0], l[1], l[2], l[3]);
  } else if (i < 339968) {                // bsc[3][4096], scaled merged bias (L0)
    int f = i - 327680;
    int g = f >> 12, j = f & 4095;
    int src = (g == 0) ? j : (g + 1) * HDIM + j;
    float sc = (g == 1) ? S2 : S1;
    ws[WS_BSC + f] = sc * (bih0[src] + bhh0[src]);
  } else if (i < 348160) {                // c1/c2 SoA records (wr block consumed)
    int f = i - 339968;
    const float* Wih = (f < 4096) ? Wih1 : Wih2;
    const float* bih = (f < 4096) ? bih1 : bih2;
    const float* bhh = (f < 4096) ? bhh1 : bhh2;
    const float* Whr = (f < 4096) ? Whr1 : Whr2;
    float* c = ws + ((f < 4096) ? WS_C1 : WS_C2);
    int j = f & 4095;
    *(float4*)(c + j * 4)         = *(const float4*)&Wih[(size_t)j * 4];
    *(float4*)(c + 16384 + j * 4) = *(const float4*)&Wih[(size_t)(2 * HDIM + j) * 4];
    *(float4*)(c + 32768 + j * 4) = *(const float4*)&Wih[(size_t)(3 * HDIM + j) * 4];
    *(float4*)(c + 49152 + j * 4) = make_float4(bih[j] + bhh[j],
                                      bih[2 * HDIM + j] + bhh[2 * HDIM + j],
                                      bih[3 * HDIM + j] + bhh[3 * HDIM + j], 0.f);
    *(float4*)(c + 65536 + j * 4) = make_float4(Whr[j], Whr[HDIM + j], Whr[2 * HDIM + j], Whr[3 * HDIM + j]);
  } else if (i < 446464) {                // bp: small-layer MFMA B-frags
    int f = i - 348160;                   // 98304 threads, one 16B frag each
    int lane = f & 63;
    int tg = f >> 6;                      // (L*3+g)*256 + tile, 0..1535
    int L = tg / 768;
    int r2 = tg - L * 768;
    int g = r2 >> 8, tile = r2 & 255;
    const float* Wih = (L == 0) ? Wih1 : Wih2;
    const float* bih = (L == 0) ? bih1 : bih2;
    const float* bhh = (L == 0) ? bhh1 : bhh2;
    int q = lane >> 4, n = lane & 15;
    int j = tile * 16 + n;
    int go = (g == 0) ? 0 : (g + 1) * HDIM;    // PyTorch gate rows i,g,o
    u16 v[8] = {0, 0, 0, 0, 0, 0, 0, 0};
    if (q < 2) {
#pragma unroll
      for (int e = 0; e < 8; ++e) {
        float wv = Wih[(size_t)(go + j) * 4 + (e & 3)];
        u16 h, l;
        hilo(wv, h, l);
        v[e] = (q == 0) ? h : l;
      }
    } else if (q == 2) {
      float bv = bih[go + j] + bhh[go + j];
      hilo(bv, v[0], v[1]);
    }
    u16* bpp = (u16*)(ws + WS_BP);
    // r21: gate-contiguous layout [L][tile][gate][lane][8]
    size_t f2 = (((size_t)L * 256 + tile) * 3 + g) * 64 + lane;
    *(short8*)&bpp[f2 * 8] =
        (short8){(short)v[0], (short)v[1], (short)v[2], (short)v[3],
                 (short)v[4], (short)v[5], (short)v[6], (short)v[7]};
  }
}

// Layer 0 v3 (r24): r17's lx-drop extended to lw_lo -- the SAME swizzle
// cancellation holds for W (store: LDS row r chunk c holds global chunk
// c^(r&7); read at chunk (kc*4+q)^(m&7) of a row with low-3-bits m&7 ->
// content chunk kc*4+q), so bl reads straight from global wlo at the
// unswizzled column: bit-identical fragments. All 4 waves read the SAME
// W rows -> L1/L2-hot. LDS 48K->24K, 24 staged units, launch_bounds(256,5)
// -> 5 blocks/CU = 20 waves/CU (was 12). Attacks the measured latency-bound
// profile (MfmaUtil 21 / VALUBusy 47 / Occ 26 -- no pipe half-busy).
__global__ __launch_bounds__(256, 5)
void lstm_layer0_mfma(const u16* __restrict__ xhi, const u16* __restrict__ xlo,
                      const u16* __restrict__ whi, const u16* __restrict__ wlo,
                      const float* __restrict__ bsc, const float* __restrict__ Whr,
                      float* __restrict__ pp) {
  __shared__ __align__(16) char smem[24576];
  u16* lw_hi = (u16*)smem;                 // [192 rows = g*64+j][64 k] swizzled

  const int tid = threadIdx.x;
  const int w = tid >> 6, lane = tid & 63;
  const int m = lane & 15, q = lane >> 4;
  const int jb = blockIdx.x & 63, tbb = blockIdx.x >> 6;
  const int j0 = jb * 64;
  const int t0 = tbb * 256;

  const int r8_ = lane >> 3;
  const int swo = ((lane & 7) ^ r8_) * 8;

  // ---- stage W_hi (24 x 1KB units); 6 units/wave
#pragma unroll
  for (int ui = 0; ui < 6; ++ui) {
    const int u = w * 6 + ui;
    gload16(whi + (size_t)((u >> 3) * HDIM + j0 + (u & 7) * 8 + r8_) * 64 + swo,
            smem + u * 1024);
  }

  // per-lane constants reused by both tiles (fly under the DMA)
  float whr_v[4][4];
#pragma unroll
  for (int p = 0; p < 4; ++p)
#pragma unroll
    for (int js = 0; js < 4; ++js)
      whr_v[p][js] = Whr[(size_t)p * HDIM + j0 + js * 16 + m];
  float biv[4], bgv[4], bov[4];
#pragma unroll
  for (int js = 0; js < 4; ++js) {
    const int j = j0 + js * 16 + m;
    biv[js] = bsc[j];
    bgv[js] = bsc[HDIM + j];
    bov[js] = bsc[2 * HDIM + j];
  }

  f32x4 acc[2][4][3];
  short8 al[2][2];

  auto zero_acc = [&]() {
#pragma unroll
    for (int ts = 0; ts < 2; ++ts)
#pragma unroll
      for (int js = 0; js < 4; ++js)
#pragma unroll
        for (int g = 0; g < 3; ++g) acc[ts][js][g] = (f32x4){0.f, 0.f, 0.f, 0.f};
  };
  auto load_al = [&](int tt) {
#pragma unroll
    for (int kc = 0; kc < 2; ++kc)
#pragma unroll
      for (int ts = 0; ts < 2; ++ts)
        al[kc][ts] = *(const short8*)&xlo[(size_t)(t0 + tt * 128 + w * 32 + ts * 16 + m) * KDIM + kc * 32 + q * 8];
  };
  auto compute = [&](int tt) {
#pragma unroll
    for (int kc = 0; kc < 2; ++kc) {
      short8 ah[2];
#pragma unroll
      for (int ts = 0; ts < 2; ++ts)
        ah[ts] = *(const short8*)&xhi[(size_t)(t0 + tt * 128 + w * 32 + ts * 16 + m) * KDIM + kc * 32 + q * 8];
      const int cs = ((kc * 4 + q) ^ (m & 7)) * 8;
      const int ko = (kc * 4 + q) * 8;         // unswizzled col for global W reads
#pragma unroll
      for (int js = 0; js < 4; ++js) {
#pragma unroll
        for (int g = 0; g < 3; ++g) {
          const int roff = (g * 64 + js * 16 + m) * 64 + cs;
          short8 bh = *(const short8*)&lw_hi[roff];
          short8 bl = *(const short8*)&wlo[(size_t)(g * HDIM + j0 + js * 16 + m) * KDIM + ko];
#pragma unroll
          for (int ts = 0; ts < 2; ++ts) {
            acc[ts][js][g] = __builtin_amdgcn_mfma_f32_16x16x32_bf16(ah[ts], bh, acc[ts][js][g], 0, 0, 0);
            acc[ts][js][g] = __builtin_amdgcn_mfma_f32_16x16x32_bf16(al[kc][ts], bh, acc[ts][js][g], 0, 0, 0);
            acc[ts][js][g] = __builtin_amdgcn_mfma_f32_16x16x32_bf16(ah[ts], bl, acc[ts][js][g], 0, 0, 0);
          }
        }
      }
    }
  };
  auto act_proj = [&](int tt) {
    float hreg[2][4][4];
#pragma unroll
    for (int js = 0; js < 4; ++js) {
#pragma unroll
      for (int ts = 0; ts < 2; ++ts) {
#pragma unroll
        for (int r = 0; r < 4; ++r) {
          float ea = EXP2(acc[ts][js][0][r] + biv[js]);       // e^-i
          float eb = EXP2(acc[ts][js][1][r] + bgv[js]);       // e^-2g
          float c = (1.0f - eb) * rcpf((1.0f + ea) * (1.0f + eb));  // sig(i)tanh(g)
          float ec = EXP2(acc[ts][js][2][r] + bov[js]);       // e^-o
          hreg[ts][js][r] = h_merge(c, ec);                   // tanh(c)sig(o)
        }
      }
    }
    // projection partial over this lane's 4 js, then butterfly over 16 m-lanes
#pragma unroll
    for (int ts = 0; ts < 2; ++ts) {
#pragma unroll
      for (int r = 0; r < 4; ++r) {
        float pv[4];
#pragma unroll
        for (int p = 0; p < 4; ++p) {
          float s = 0.f;
#pragma unroll
          for (int js = 0; js < 4; ++js) s = fmaf(hreg[ts][js][r], whr_v[p][js], s);
#pragma unroll
          for (int ofs = 1; ofs < 16; ofs <<= 1) s += __shfl_xor(s, ofs, 16);
          pv[p] = s;
        }
        if (m == 0) {
          const int t = t0 + tt * 128 + w * 32 + ts * 16 + q * 4 + r;
          *(float4*)&pp[((size_t)jb * TSTEPS + t) * PDIM] = make_float4(pv[0], pv[1], pv[2], pv[3]);
        }
      }
    }
  };

  // ---- tile 0
  load_al(0);
  zero_acc();
  __syncthreads();                 // drain W_hi DMA (only barrier in the kernel)
  compute(0);
  load_al(1);
  act_proj(0);
  zero_acc();
  compute(1);
  act_proj(1);
}

// FUSED post-L0 (r21, kept): ONE launch, 512 blocks x 512 threads, 16 t/blk.
// Gate-contiguous bp: one base pointer, imm offsets 0/1024/2048B, 3072B bump.
__global__ __launch_bounds__(512, 4)
void fused2(const float* __restrict__ pp, const u16* __restrict__ bp,
            const float* __restrict__ cwr1, const float* __restrict__ cwr2,
            float* __restrict__ out) {
  __shared__ __align__(16) float ytile[64];   // y[16 t][4 p] current layer input
  __shared__ float part[512];
  const int tid = threadIdx.x;
  const int lane = tid & 63, w = tid >> 6;    // w 0..7 = j-eighth
  const int n = lane & 15, qq = lane >> 4;
  const int t0 = blockIdx.x * 16;
  const f32x4 zc = (f32x4){0.f, 0.f, 0.f, 0.f};

  // ---- phase 0: reduce pp's 64 j-slices for this block's 16 t (bit-identical
  // to y0_reduce: 4 groups of serial-16, then left 4-chain).
  if (tid < 256) {
    const int o = tid & 63, sg = tid >> 6;
    float s = 0.f;
#pragma unroll 4
    for (int k = sg * 16; k < sg * 16 + 16; ++k)
      s += pp[(size_t)k * (TSTEPS * PDIM) + t0 * PDIM + o];
    part[sg * 64 + o] = s;
  }
  __syncthreads();
  if (tid < 64) ytile[tid] = ((part[tid] + part[64 + tid]) + part[128 + tid]) + part[192 + tid];
  __syncthreads();

#pragma unroll
  for (int L = 0; L < 2; ++L) {
    const u16* bL = bp + (size_t)L * 393216;
    const float4* cwr = (const float4*)((L == 0) ? cwr1 : cwr2);

    // A fragment: lane row m = n holds y[t0+n]; K-slots per prep scheme
    float4 yv = *(const float4*)&ytile[n * 4];
    float ye[4] = {yv.x, yv.y, yv.z, yv.w};
    u16 yh[4], yl[4];
#pragma unroll
    for (int e = 0; e < 4; ++e) hilo(ye[e], yh[e], yl[e]);
    short8 af = (short8){0, 0, 0, 0, 0, 0, 0, 0};
    if (qq < 2) {
      af[0] = (short)yh[0]; af[1] = (short)yh[1]; af[2] = (short)yh[2]; af[3] = (short)yh[3];
      af[4] = (short)yl[0]; af[5] = (short)yl[1]; af[6] = (short)yl[2]; af[7] = (short)yl[3];
    } else if (qq == 2) {
      af[0] = (short)0x3F80;                  // 1.0 at k16 (b_hi), k17 (b_lo)
      af[1] = (short)0x3F80;
    }

    float o_[4][4];
#pragma unroll
    for (int r = 0; r < 4; ++r)
#pragma unroll
      for (int p = 0; p < 4; ++p) o_[r][p] = 0.f;

    // one base pointer per wave-lane: tile = w*32+jt; u16 stride/tile = 1536
    const u16* bptr = bL + (size_t)(w * 32) * 1536 + (size_t)lane * 8;
    const float4* wptr = cwr + (size_t)(w * 32) * 16 + n;
#pragma unroll 4
    for (int jt = 0; jt < 32; ++jt) {
      short8 bfi = *(const short8*)(bptr);          // gate i: +0B
      short8 bfg = *(const short8*)(bptr + 512);    // gate g: +1024B
      short8 bfo = *(const short8*)(bptr + 1024);   // gate o: +2048B
      float4 wr = *wptr;                            // Whr[0..3][j], j=tile*16+n
      f32x4 ai = __builtin_amdgcn_mfma_f32_16x16x32_bf16(af, bfi, zc, 0, 0, 0);
      f32x4 ag = __builtin_amdgcn_mfma_f32_16x16x32_bf16(af, bfg, zc, 0, 0, 0);
      f32x4 ao = __builtin_amdgcn_mfma_f32_16x16x32_bf16(af, bfo, zc, 0, 0, 0);
#pragma unroll
      for (int r = 0; r < 4; ++r) {            // C-layout: col j = n, row t = qq*4+r
        float cc = sig_poly(ai[r]) * tanh_poly(ag[r]);
        float h = tanh_poly(cc) * sig_poly(ao[r]);
        o_[r][0] = fmaf(h, wr.x, o_[r][0]);
        o_[r][1] = fmaf(h, wr.y, o_[r][1]);
        o_[r][2] = fmaf(h, wr.z, o_[r][2]);
        o_[r][3] = fmaf(h, wr.w, o_[r][3]);
      }
      bptr += 1536;
      wptr += 16;
    }

    // reduce over the 16 j-lanes
#pragma unroll
    for (int r = 0; r < 4; ++r)
#pragma unroll
      for (int p = 0; p < 4; ++p) {
#pragma unroll
        for (int ofs = 1; ofs < 16; ofs <<= 1)
          o_[r][p] += __shfl_xor(o_[r][p], ofs, 16);
      }
    __syncthreads();                           // part free for reuse
    if (n == 0) {
#pragma unroll
      for (int r = 0; r < 4; ++r)
#pragma unroll
        for (int p = 0; p < 4; ++p)
          part[w * 64 + (qq * 4 + r) * 4 + p] = o_[r][p];
    }
    __syncthreads();
    if (tid < 64) {
      float s = part[tid];
#pragma unroll
      for (int w2 = 1; w2 < 8; ++w2) s += part[w2 * 64 + tid];
      ytile[tid] = s;
    }
    __syncthreads();
  }

  // ---- final out: 64 consecutive floats per block, coalesced
  if (tid < 64) out[t0 * PDIM + tid] = ytile[tid];
}

extern "C" void kernel_launch(void* const* d_in, const int* in_sizes, int n_in,
                              void* d_out, int out_size, void* d_ws, size_t ws_size,
                              hipStream_t stream) {
  const float* x    = (const float*)d_in[0];
  const float* Wih0 = (const float*)d_in[1];
  const float* bih0 = (const float*)d_in[3];
  const float* bhh0 = (const float*)d_in[4];
  const float* Whr0 = (const float*)d_in[5];
  const float* Wih1 = (const float*)d_in[6];
  const float* bih1 = (const float*)d_in[8];
  const float* bhh1 = (const float*)d_in[9];
  const float* Whr1 = (const float*)d_in[10];
  const float* Wih2 = (const float*)d_in[11];
  const float* bih2 = (const float*)d_in[13];
  const float* bhh2 = (const float*)d_in[14];
  const float* Whr2 = (const float*)d_in[15];
  float* out = (float*)d_out;
  float* ws = (float*)d_ws;
  float* pp = ws + WS_PP;
  const u16* bp = (const u16*)(ws + WS_BP);

  prep_kernel<<<dim3(1744), dim3(256), 0, stream>>>(
      x, Wih0, bih0, bhh0, Wih1, bih1, bhh1, Whr1, Wih2, bih2, bhh2, Whr2, ws);

  lstm_layer0_mfma<<<dim3(2048), dim3(256), 0, stream>>>(
      (const u16*)(ws + WS_XHI), (const u16*)(ws + WS_XLO),
      (const u16*)(ws + WS_WHI), (const u16*)(ws + WS_WLO),
      ws + WS_BSC, Whr0, pp);

  fused2<<<dim3(512), dim3(512), 0, stream>>>(
      pp, bp, ws + WS_C1 + 65536, ws + WS_C2 + 65536, out);
}

// Round 14
// 209.323 us; speedup vs baseline: 3.0045x; 3.0045x over previous
//
#include <hip/hip_runtime.h>

#define TSTEPS 8192
#define HDIM 4096
#define PDIM 4
#define KDIM 64

typedef unsigned short u16;
typedef __attribute__((ext_vector_type(8))) short short8;
typedef __attribute__((ext_vector_type(4))) float f32x4;

#define S1 -1.44269504089f   // -log2(e)
#define S2 -2.88539008177f   // -2*log2(e)

#if __has_builtin(__builtin_amdgcn_exp2f)
#define EXP2(x) __builtin_amdgcn_exp2f(x)
#else
#define EXP2(x) exp2f(x)
#endif
__device__ __forceinline__ float rcpf(float x) { return __builtin_amdgcn_rcpf(x); }

// tanh(c)*sig(o) for c in (-1,1), given ec = e^-o. Pade CF-7 tanh (err ~5e-6)
// merged into sig's rcp (r10 form -- best measured for L0 epilogue).
__device__ __forceinline__ float h_merge(float c, float ec) {
  float c2 = c * c;
  float num = c * fmaf(c2, 10.0f, 105.0f);
  float den = fmaf(c2, 45.0f, 105.0f) + c2 * c2;
  return num * rcpf(den * (1.0f + ec));
}

// Polynomial sig/tanh for SMALL-LAYER gates only (|z| <= ~0.6, 5-sigma; poly
// valid to |z|~1 at ~2e-5 err).
__device__ __forceinline__ float sig_poly(float z) {
  float z2 = z * z;
  float q = fmaf(z2, -2.1081349e-4f, 2.0833333e-3f);   // -17/80640, 1/480
  q = fmaf(z2, q, -2.0833333e-2f);                     // -1/48
  q = fmaf(z2, q, 0.25f);                              // 1/4
  return fmaf(z, q, 0.5f);
}
__device__ __forceinline__ float tanh_poly(float z) {
  float z2 = z * z;
  float q = fmaf(z2, -5.3968254e-2f, 1.3333333e-1f);   // -17/315, 2/15
  q = fmaf(z2, q, -3.3333333e-1f);                     // -1/3
  q = fmaf(z2, q, 1.0f);
  return z * q;
}

// async global->LDS DMA, 16B per lane; LDS dest = uniform base + lane*16
__device__ __forceinline__ void gload16(const void* g, void* l) {
  __builtin_amdgcn_global_load_lds((const __attribute__((address_space(1))) unsigned int*)g,
                                   (__attribute__((address_space(3))) unsigned int*)l,
                                   16, 0, 0);
}

__device__ __forceinline__ u16 bf16_rne(float f) {
  unsigned u = __float_as_uint(f);
  u += 0x7FFF + ((u >> 16) & 1);
  return (u16)(u >> 16);
}
__device__ __forceinline__ void hilo(float v, u16& h, u16& l) {
  h = bf16_rne(v);
  l = bf16_rne(v - __uint_as_float((unsigned)h << 16));
}

// ---- workspace layout (float offsets) ----
#define WS_Y0   0
#define WS_Y1   32768
#define WS_BSC  65536
#define WS_C1   77824
#define WS_C2   159744
#define WS_XHI  241664
#define WS_XLO  503808
#define WS_WHI  765952
#define WS_WLO  1159168
#define WS_PP   1552384
#define WS_BP   3649536
// bp (r21 layout, GATE-CONTIGUOUS): [L][tile][gate][lane][8 u16] -- the 3
// gate frags of one tile are 1KB apart so fused2 reads them from ONE base
// pointer with immediate offsets 0/1024/2048B. 786432 u16 total as before.

// One-shot prep (single launch; r23 probe measured its warm cost at ~1-2us).
__global__ void prep_kernel(const float* __restrict__ x,
                            const float* __restrict__ Wih0, const float* __restrict__ bih0,
                            const float* __restrict__ bhh0,
                            const float* __restrict__ Wih1, const float* __restrict__ bih1,
                            const float* __restrict__ bhh1, const float* __restrict__ Whr1,
                            const float* __restrict__ Wih2, const float* __restrict__ bih2,
                            const float* __restrict__ bhh2, const float* __restrict__ Whr2,
                            float* __restrict__ ws) {
  const int i = blockIdx.x * 256 + threadIdx.x;
  u16* xhi = (u16*)(ws + WS_XHI);
  u16* xlo = (u16*)(ws + WS_XLO);
  u16* whi = (u16*)(ws + WS_WHI);
  u16* wlo = (u16*)(ws + WS_WLO);

  if (i < 131072) {                       // x: 131072 float4 units, unscaled
    float4 v = *(const float4*)&x[i * 4];
    float val[4] = {v.x, v.y, v.z, v.w};
    u16 h[4], l[4];
#pragma unroll
    for (int e = 0; e < 4; ++e) hilo(val[e], h[e], l[e]);
    *(ushort4*)&xhi[i * 4] = make_ushort4(h[0], h[1], h[2], h[3]);
    *(ushort4*)&xlo[i * 4] = make_ushort4(l[0], l[1], l[2], l[3]);
  } else if (i < 327680) {                // W_ih0: 196608 float4 units, scaled
    int f = i - 131072;
    int el4 = f * 4;
    int r = el4 >> 6;                     // packed row 0..12287 ([gate][j])
    int k4 = el4 & 63;
    int gate = r >> 12, jr = r & 4095;
    int src = (gate == 0) ? jr : (gate + 1) * HDIM + jr;   // i,g,o = rows 0,2H,3H
    float sc = (gate == 1) ? S2 : S1;
    float4 v = *(const float4*)&Wih0[(size_t)src * KDIM + k4];
    float val[4] = {sc * v.x, sc * v.y, sc * v.z, sc * v.w};
    u16 h[4], l[4];
#pragma unroll
    for (int e = 0; e < 4; ++e) hilo(val[e], h[e], l[e]);
    *(ushort4*)&whi[r * KDIM + k4] = make_ushort4(h[0], h[1], h[2], h[3]);
    *(ushort4*)&wlo[r * KDIM + k4] = make_ushort4(l[0], l[1], l[2], l[3]);
  } else if (i < 339968) {                // bsc[3][4096], scaled merged bias (L0)
    int f = i - 327680;
    int g = f >> 12, j = f & 4095;
    int src = (g == 0) ? j : (g + 1) * HDIM + j;
    float sc = (g == 1) ? S2 : S1;
    ws[WS_BSC + f] = sc * (bih0[src] + bhh0[src]);
  } else if (i < 348160) {                // c1/c2 SoA records (wr block consumed)
    int f = i - 339968;
    const float* Wih = (f < 4096) ? Wih1 : Wih2;
    const float* bih = (f < 4096) ? bih1 : bih2;
    const float* bhh = (f < 4096) ? bhh1 : bhh2;
    const float* Whr = (f < 4096) ? Whr1 : Whr2;
    float* c = ws + ((f < 4096) ? WS_C1 : WS_C2);
    int j = f & 4095;
    *(float4*)(c + j * 4)         = *(const float4*)&Wih[(size_t)j * 4];
    *(float4*)(c + 16384 + j * 4) = *(const float4*)&Wih[(size_t)(2 * HDIM + j) * 4];
    *(float4*)(c + 32768 + j * 4) = *(const float4*)&Wih[(size_t)(3 * HDIM + j) * 4];
    *(float4*)(c + 49152 + j * 4) = make_float4(bih[j] + bhh[j],
                                      bih[2 * HDIM + j] + bhh[2 * HDIM + j],
                                      bih[3 * HDIM + j] + bhh[3 * HDIM + j], 0.f);
    *(float4*)(c + 65536 + j * 4) = make_float4(Whr[j], Whr[HDIM + j], Whr[2 * HDIM + j], Whr[3 * HDIM + j]);
  } else if (i < 446464) {                // bp: small-layer MFMA B-frags
    int f = i - 348160;                   // 98304 threads, one 16B frag each
    int lane = f & 63;
    int tg = f >> 6;                      // (L*3+g)*256 + tile, 0..1535
    int L = tg / 768;
    int r2 = tg - L * 768;
    int g = r2 >> 8, tile = r2 & 255;
    const float* Wih = (L == 0) ? Wih1 : Wih2;
    const float* bih = (L == 0) ? bih1 : bih2;
    const float* bhh = (L == 0) ? bhh1 : bhh2;
    int q = lane >> 4, n = lane & 15;
    int j = tile * 16 + n;
    int go = (g == 0) ? 0 : (g + 1) * HDIM;    // PyTorch gate rows i,g,o
    u16 v[8] = {0, 0, 0, 0, 0, 0, 0, 0};
    if (q < 2) {
#pragma unroll
      for (int e = 0; e < 8; ++e) {
        float wv = Wih[(size_t)(go + j) * 4 + (e & 3)];
        u16 h, l;
        hilo(wv, h, l);
        v[e] = (q == 0) ? h : l;
      }
    } else if (q == 2) {
      float bv = bih[go + j] + bhh[go + j];
      hilo(bv, v[0], v[1]);
    }
    u16* bpp = (u16*)(ws + WS_BP);
    // r21: gate-contiguous layout [L][tile][gate][lane][8]
    size_t f2 = (((size_t)L * 256 + tile) * 3 + g) * 64 + lane;
    *(short8*)&bpp[f2 * 8] =
        (short8){(short)v[0], (short)v[1], (short)v[2], (short)v[3],
                 (short)v[4], (short)v[5], (short)v[6], (short)v[7]};
  }
}

// Layer 0 v2 (r17/r21, REVERTED from the r24 v3 disaster): 48K LDS stages
// BOTH W halves (W frags are re-read per (kc,ts) -- staging is load-bearing;
// only the once-read x frags can stream from global). launch_bounds(256,3),
// 84 VGPR, ~74-75.5us measured on three healthy containers. r24's (256,5)
// cap spilled the 96-f32 accumulator to scratch (VGPR_Count 48, WRITE 892MB)
// and per-MFMA wlo reads added 400MB of HBM -- 507us. L0 is at its
// structural equilibrium; no further changes.
__global__ __launch_bounds__(256, 3)
void lstm_layer0_mfma(const u16* __restrict__ xhi, const u16* __restrict__ xlo,
                      const u16* __restrict__ whi, const u16* __restrict__ wlo,
                      const float* __restrict__ bsc, const float* __restrict__ Whr,
                      float* __restrict__ pp) {
  __shared__ __align__(16) char smem[49152];
  u16* lw_hi = (u16*)smem;                 // [192 rows = g*64+j][64 k] swizzled
  u16* lw_lo = (u16*)(smem + 24576);

  const int tid = threadIdx.x;
  const int w = tid >> 6, lane = tid & 63;
  const int m = lane & 15, q = lane >> 4;
  const int jb = blockIdx.x & 63, tbb = blockIdx.x >> 6;
  const int j0 = jb * 64;
  const int t0 = tbb * 256;

  const int r8_ = lane >> 3;
  const int swo = ((lane & 7) ^ r8_) * 8;

  // ---- stage W (48 x 1KB units); 12 units/wave
#pragma unroll
  for (int ui = 0; ui < 12; ++ui) {
    const int u = w * 12 + ui;
    const u16* g;
    if (u < 24) {
      g = whi + (size_t)((u >> 3) * HDIM + j0 + (u & 7) * 8 + r8_) * 64 + swo;
    } else {
      const int uu = u - 24;
      g = wlo + (size_t)((uu >> 3) * HDIM + j0 + (uu & 7) * 8 + r8_) * 64 + swo;
    }
    gload16(g, smem + u * 1024);
  }

  // per-lane constants reused by both tiles (fly under the DMA)
  float whr_v[4][4];
#pragma unroll
  for (int p = 0; p < 4; ++p)
#pragma unroll
    for (int js = 0; js < 4; ++js)
      whr_v[p][js] = Whr[(size_t)p * HDIM + j0 + js * 16 + m];
  float biv[4], bgv[4], bov[4];
#pragma unroll
  for (int js = 0; js < 4; ++js) {
    const int j = j0 + js * 16 + m;
    biv[js] = bsc[j];
    bgv[js] = bsc[HDIM + j];
    bov[js] = bsc[2 * HDIM + j];
  }

  f32x4 acc[2][4][3];
  short8 al[2][2];

  auto zero_acc = [&]() {
#pragma unroll
    for (int ts = 0; ts < 2; ++ts)
#pragma unroll
      for (int js = 0; js < 4; ++js)
#pragma unroll
        for (int g = 0; g < 3; ++g) acc[ts][js][g] = (f32x4){0.f, 0.f, 0.f, 0.f};
  };
  auto load_al = [&](int tt) {
#pragma unroll
    for (int kc = 0; kc < 2; ++kc)
#pragma unroll
      for (int ts = 0; ts < 2; ++ts)
        al[kc][ts] = *(const short8*)&xlo[(size_t)(t0 + tt * 128 + w * 32 + ts * 16 + m) * KDIM + kc * 32 + q * 8];
  };
  auto compute = [&](int tt) {
#pragma unroll
    for (int kc = 0; kc < 2; ++kc) {
      short8 ah[2];
#pragma unroll
      for (int ts = 0; ts < 2; ++ts)
        ah[ts] = *(const short8*)&xhi[(size_t)(t0 + tt * 128 + w * 32 + ts * 16 + m) * KDIM + kc * 32 + q * 8];
      const int cs = ((kc * 4 + q) ^ (m & 7)) * 8;
#pragma unroll
      for (int js = 0; js < 4; ++js) {
#pragma unroll
        for (int g = 0; g < 3; ++g) {
          const int roff = (g * 64 + js * 16 + m) * 64 + cs;
          short8 bh = *(const short8*)&lw_hi[roff];
          short8 bl = *(const short8*)&lw_lo[roff];
#pragma unroll
          for (int ts = 0; ts < 2; ++ts) {
            acc[ts][js][g] = __builtin_amdgcn_mfma_f32_16x16x32_bf16(ah[ts], bh, acc[ts][js][g], 0, 0, 0);
            acc[ts][js][g] = __builtin_amdgcn_mfma_f32_16x16x32_bf16(al[kc][ts], bh, acc[ts][js][g], 0, 0, 0);
            acc[ts][js][g] = __builtin_amdgcn_mfma_f32_16x16x32_bf16(ah[ts], bl, acc[ts][js][g], 0, 0, 0);
          }
        }
      }
    }
  };
  auto act_proj = [&](int tt) {
    float hreg[2][4][4];
#pragma unroll
    for (int js = 0; js < 4; ++js) {
#pragma unroll
      for (int ts = 0; ts < 2; ++ts) {
#pragma unroll
        for (int r = 0; r < 4; ++r) {
          float ea = EXP2(acc[ts][js][0][r] + biv[js]);       // e^-i
          float eb = EXP2(acc[ts][js][1][r] + bgv[js]);       // e^-2g
          float c = (1.0f - eb) * rcpf((1.0f + ea) * (1.0f + eb));  // sig(i)tanh(g)
          float ec = EXP2(acc[ts][js][2][r] + bov[js]);       // e^-o
          hreg[ts][js][r] = h_merge(c, ec);                   // tanh(c)sig(o)
        }
      }
    }
    // projection partial over this lane's 4 js, then butterfly over 16 m-lanes
#pragma unroll
    for (int ts = 0; ts < 2; ++ts) {
#pragma unroll
      for (int r = 0; r < 4; ++r) {
        float pv[4];
#pragma unroll
        for (int p = 0; p < 4; ++p) {
          float s = 0.f;
#pragma unroll
          for (int js = 0; js < 4; ++js) s = fmaf(hreg[ts][js][r], whr_v[p][js], s);
#pragma unroll
          for (int ofs = 1; ofs < 16; ofs <<= 1) s += __shfl_xor(s, ofs, 16);
          pv[p] = s;
        }
        if (m == 0) {
          const int t = t0 + tt * 128 + w * 32 + ts * 16 + q * 4 + r;
          *(float4*)&pp[((size_t)jb * TSTEPS + t) * PDIM] = make_float4(pv[0], pv[1], pv[2], pv[3]);
        }
      }
    }
  };

  // ---- tile 0
  load_al(0);
  zero_acc();
  __syncthreads();                 // drain W DMA (only barrier in the kernel)
  compute(0);
  load_al(1);
  act_proj(0);
  zero_acc();
  compute(1);
  act_proj(1);
}

// FUSED post-L0 (r21, kept): ONE launch, 512 blocks x 512 threads, 16 t/blk.
// Gate-contiguous bp: one base pointer, imm offsets 0/1024/2048B, 3072B bump.
__global__ __launch_bounds__(512, 4)
void fused2(const float* __restrict__ pp, const u16* __restrict__ bp,
            const float* __restrict__ cwr1, const float* __restrict__ cwr2,
            float* __restrict__ out) {
  __shared__ __align__(16) float ytile[64];   // y[16 t][4 p] current layer input
  __shared__ float part[512];
  const int tid = threadIdx.x;
  const int lane = tid & 63, w = tid >> 6;    // w 0..7 = j-eighth
  const int n = lane & 15, qq = lane >> 4;
  const int t0 = blockIdx.x * 16;
  const f32x4 zc = (f32x4){0.f, 0.f, 0.f, 0.f};

  // ---- phase 0: reduce pp's 64 j-slices for this block's 16 t (bit-identical
  // to y0_reduce: 4 groups of serial-16, then left 4-chain).
  if (tid < 256) {
    const int o = tid & 63, sg = tid >> 6;
    float s = 0.f;
#pragma unroll 4
    for (int k = sg * 16; k < sg * 16 + 16; ++k)
      s += pp[(size_t)k * (TSTEPS * PDIM) + t0 * PDIM + o];
    part[sg * 64 + o] = s;
  }
  __syncthreads();
  if (tid < 64) ytile[tid] = ((part[tid] + part[64 + tid]) + part[128 + tid]) + part[192 + tid];
  __syncthreads();

#pragma unroll
  for (int L = 0; L < 2; ++L) {
    const u16* bL = bp + (size_t)L * 393216;
    const float4* cwr = (const float4*)((L == 0) ? cwr1 : cwr2);

    // A fragment: lane row m = n holds y[t0+n]; K-slots per prep scheme
    float4 yv = *(const float4*)&ytile[n * 4];
    float ye[4] = {yv.x, yv.y, yv.z, yv.w};
    u16 yh[4], yl[4];
#pragma unroll
    for (int e = 0; e < 4; ++e) hilo(ye[e], yh[e], yl[e]);
    short8 af = (short8){0, 0, 0, 0, 0, 0, 0, 0};
    if (qq < 2) {
      af[0] = (short)yh[0]; af[1] = (short)yh[1]; af[2] = (short)yh[2]; af[3] = (short)yh[3];
      af[4] = (short)yl[0]; af[5] = (short)yl[1]; af[6] = (short)yl[2]; af[7] = (short)yl[3];
    } else if (qq == 2) {
      af[0] = (short)0x3F80;                  // 1.0 at k16 (b_hi), k17 (b_lo)
      af[1] = (short)0x3F80;
    }

    float o_[4][4];
#pragma unroll
    for (int r = 0; r < 4; ++r)
#pragma unroll
      for (int p = 0; p < 4; ++p) o_[r][p] = 0.f;

    // one base pointer per wave-lane: tile = w*32+jt; u16 stride/tile = 1536
    const u16* bptr = bL + (size_t)(w * 32) * 1536 + (size_t)lane * 8;
    const float4* wptr = cwr + (size_t)(w * 32) * 16 + n;
#pragma unroll 4
    for (int jt = 0; jt < 32; ++jt) {
      short8 bfi = *(const short8*)(bptr);          // gate i: +0B
      short8 bfg = *(const short8*)(bptr + 512);    // gate g: +1024B
      short8 bfo = *(const short8*)(bptr + 1024);   // gate o: +2048B
      float4 wr = *wptr;                            // Whr[0..3][j], j=tile*16+n
      f32x4 ai = __builtin_amdgcn_mfma_f32_16x16x32_bf16(af, bfi, zc, 0, 0, 0);
      f32x4 ag = __builtin_amdgcn_mfma_f32_16x16x32_bf16(af, bfg, zc, 0, 0, 0);
      f32x4 ao = __builtin_amdgcn_mfma_f32_16x16x32_bf16(af, bfo, zc, 0, 0, 0);
#pragma unroll
      for (int r = 0; r < 4; ++r) {            // C-layout: col j = n, row t = qq*4+r
        float cc = sig_poly(ai[r]) * tanh_poly(ag[r]);
        float h = tanh_poly(cc) * sig_poly(ao[r]);
        o_[r][0] = fmaf(h, wr.x, o_[r][0]);
        o_[r][1] = fmaf(h, wr.y, o_[r][1]);
        o_[r][2] = fmaf(h, wr.z, o_[r][2]);
        o_[r][3] = fmaf(h, wr.w, o_[r][3]);
      }
      bptr += 1536;
      wptr += 16;
    }

    // reduce over the 16 j-lanes
#pragma unroll
    for (int r = 0; r < 4; ++r)
#pragma unroll
      for (int p = 0; p < 4; ++p) {
#pragma unroll
        for (int ofs = 1; ofs < 16; ofs <<= 1)
          o_[r][p] += __shfl_xor(o_[r][p], ofs, 16);
      }
    __syncthreads();                           // part free for reuse
    if (n == 0) {
#pragma unroll
      for (int r = 0; r < 4; ++r)
#pragma unroll
        for (int p = 0; p < 4; ++p)
          part[w * 64 + (qq * 4 + r) * 4 + p] = o_[r][p];
    }
    __syncthreads();
    if (tid < 64) {
      float s = part[tid];
#pragma unroll
      for (int w2 = 1; w2 < 8; ++w2) s += part[w2 * 64 + tid];
      ytile[tid] = s;
    }
    __syncthreads();
  }

  // ---- final out: 64 consecutive floats per block, coalesced
  if (tid < 64) out[t0 * PDIM + tid] = ytile[tid];
}

extern "C" void kernel_launch(void* const* d_in, const int* in_sizes, int n_in,
                              void* d_out, int out_size, void* d_ws, size_t ws_size,
                              hipStream_t stream) {
  const float* x    = (const float*)d_in[0];
  const float* Wih0 = (const float*)d_in[1];
  const float* bih0 = (const float*)d_in[3];
  const float* bhh0 = (const float*)d_in[4];
  const float* Whr0 = (const float*)d_in[5];
  const float* Wih1 = (const float*)d_in[6];
  const float* bih1 = (const float*)d_in[8];
  const float* bhh1 = (const float*)d_in[9];
  const float* Whr1 = (const float*)d_in[10];
  const float* Wih2 = (const float*)d_in[11];
  const float* bih2 = (const float*)d_in[13];
  const float* bhh2 = (const float*)d_in[14];
  const float* Whr2 = (const float*)d_in[15];
  float* out = (float*)d_out;
  float* ws = (float*)d_ws;
  float* pp = ws + WS_PP;
  const u16* bp = (const u16*)(ws + WS_BP);

  prep_kernel<<<dim3(1744), dim3(256), 0, stream>>>(
      x, Wih0, bih0, bhh0, Wih1, bih1, bhh1, Whr1, Wih2, bih2, bhh2, Whr2, ws);

  lstm_layer0_mfma<<<dim3(2048), dim3(256), 0, stream>>>(
      (const u16*)(ws + WS_XHI), (const u16*)(ws + WS_XLO),
      (const u16*)(ws + WS_WHI), (const u16*)(ws + WS_WLO),
      ws + WS_BSC, Whr0, pp);

  fused2<<<dim3(512), dim3(512), 0, stream>>>(
      pp, bp, ws + WS_C1 + 65536, ws + WS_C2 + 65536, out);
}

// Round 15
// 201.843 us; speedup vs baseline: 3.1159x; 1.0371x over previous
//
#include <hip/hip_runtime.h>

#define TSTEPS 8192
#define HDIM 4096
#define PDIM 4
#define KDIM 64

typedef unsigned short u16;
typedef __attribute__((ext_vector_type(8))) short short8;
typedef __attribute__((ext_vector_type(4))) float f32x4;

#define S1 -1.44269504089f   // -log2(e)
#define S2 -2.88539008177f   // -2*log2(e)

#if __has_builtin(__builtin_amdgcn_exp2f)
#define EXP2(x) __builtin_amdgcn_exp2f(x)
#else
#define EXP2(x) exp2f(x)
#endif
__device__ __forceinline__ float rcpf(float x) { return __builtin_amdgcn_rcpf(x); }

// tanh(c)*sig(o) for c in (-1,1), given ec = e^-o. Pade CF-7 tanh (err ~5e-6)
// merged into sig's rcp (r10 form -- best measured for L0 epilogue).
__device__ __forceinline__ float h_merge(float c, float ec) {
  float c2 = c * c;
  float num = c * fmaf(c2, 10.0f, 105.0f);
  float den = fmaf(c2, 45.0f, 105.0f) + c2 * c2;
  return num * rcpf(den * (1.0f + ec));
}

// Polynomial sig/tanh for SMALL-LAYER gates only (|z| <= ~0.6, 5-sigma; poly
// valid to |z|~1 at ~2e-5 err).
__device__ __forceinline__ float sig_poly(float z) {
  float z2 = z * z;
  float q = fmaf(z2, -2.1081349e-4f, 2.0833333e-3f);   // -17/80640, 1/480
  q = fmaf(z2, q, -2.0833333e-2f);                     // -1/48
  q = fmaf(z2, q, 0.25f);                              // 1/4
  return fmaf(z, q, 0.5f);
}
__device__ __forceinline__ float tanh_poly(float z) {
  float z2 = z * z;
  float q = fmaf(z2, -5.3968254e-2f, 1.3333333e-1f);   // -17/315, 2/15
  q = fmaf(z2, q, -3.3333333e-1f);                     // -1/3
  q = fmaf(z2, q, 1.0f);
  return z * q;
}

// async global->LDS DMA, 16B per lane; LDS dest = uniform base + lane*16
__device__ __forceinline__ void gload16(const void* g, void* l) {
  __builtin_amdgcn_global_load_lds((const __attribute__((address_space(1))) unsigned int*)g,
                                   (__attribute__((address_space(3))) unsigned int*)l,
                                   16, 0, 0);
}

__device__ __forceinline__ u16 bf16_rne(float f) {
  unsigned u = __float_as_uint(f);
  u += 0x7FFF + ((u >> 16) & 1);
  return (u16)(u >> 16);
}
__device__ __forceinline__ void hilo(float v, u16& h, u16& l) {
  h = bf16_rne(v);
  l = bf16_rne(v - __uint_as_float((unsigned)h << 16));
}

// ---- workspace layout (float offsets) ----
#define WS_Y0   0
#define WS_Y1   32768
#define WS_BSC  65536
#define WS_C1   77824
#define WS_C2   159744
#define WS_XHI  241664
#define WS_XLO  503808
#define WS_WHI  765952
#define WS_WLO  1159168
#define WS_PP   1552384
#define WS_BP   3649536
// bp (r21 layout, GATE-CONTIGUOUS): [L][tile][gate][lane][8 u16].

// One-shot prep (single launch; r23 probe measured its warm cost at ~1-2us).
__global__ void prep_kernel(const float* __restrict__ x,
                            const float* __restrict__ Wih0, const float* __restrict__ bih0,
                            const float* __restrict__ bhh0,
                            const float* __restrict__ Wih1, const float* __restrict__ bih1,
                            const float* __restrict__ bhh1, const float* __restrict__ Whr1,
                            const float* __restrict__ Wih2, const float* __restrict__ bih2,
                            const float* __restrict__ bhh2, const float* __restrict__ Whr2,
                            float* __restrict__ ws) {
  const int i = blockIdx.x * 256 + threadIdx.x;
  u16* xhi = (u16*)(ws + WS_XHI);
  u16* xlo = (u16*)(ws + WS_XLO);
  u16* whi = (u16*)(ws + WS_WHI);
  u16* wlo = (u16*)(ws + WS_WLO);

  if (i < 131072) {                       // x: 131072 float4 units, unscaled
    float4 v = *(const float4*)&x[i * 4];
    float val[4] = {v.x, v.y, v.z, v.w};
    u16 h[4], l[4];
#pragma unroll
    for (int e = 0; e < 4; ++e) hilo(val[e], h[e], l[e]);
    *(ushort4*)&xhi[i * 4] = make_ushort4(h[0], h[1], h[2], h[3]);
    *(ushort4*)&xlo[i * 4] = make_ushort4(l[0], l[1], l[2], l[3]);
  } else if (i < 327680) {                // W_ih0: 196608 float4 units, scaled
    int f = i - 131072;
    int el4 = f * 4;
    int r = el4 >> 6;                     // packed row 0..12287 ([gate][j])
    int k4 = el4 & 63;
    int gate = r >> 12, jr = r & 4095;
    int src = (gate == 0) ? jr : (gate + 1) * HDIM + jr;   // i,g,o = rows 0,2H,3H
    float sc = (gate == 1) ? S2 : S1;
    float4 v = *(const float4*)&Wih0[(size_t)src * KDIM + k4];
    float val[4] = {sc * v.x, sc * v.y, sc * v.z, sc * v.w};
    u16 h[4], l[4];
#pragma unroll
    for (int e = 0; e < 4; ++e) hilo(val[e], h[e], l[e]);
    *(ushort4*)&whi[r * KDIM + k4] = make_ushort4(h[0], h[1], h[2], h[3]);
    *(ushort4*)&wlo[r * KDIM + k4] = make_ushort4(l[0], l[1], l[2], l[3]);
  } else if (i < 339968) {                // bsc[3][4096], scaled merged bias (L0)
    int f = i - 327680;
    int g = f >> 12, j = f & 4095;
    int src = (g == 0) ? j : (g + 1) * HDIM + j;
    float sc = (g == 1) ? S2 : S1;
    ws[WS_BSC + f] = sc * (bih0[src] + bhh0[src]);
  } else if (i < 348160) {                // c1/c2 SoA records (wr block consumed)
    int f = i - 339968;
    const float* Wih = (f < 4096) ? Wih1 : Wih2;
    const float* bih = (f < 4096) ? bih1 : bih2;
    const float* bhh = (f < 4096) ? bhh1 : bhh2;
    const float* Whr = (f < 4096) ? Whr1 : Whr2;
    float* c = ws + ((f < 4096) ? WS_C1 : WS_C2);
    int j = f & 4095;
    *(float4*)(c + j * 4)         = *(const float4*)&Wih[(size_t)j * 4];
    *(float4*)(c + 16384 + j * 4) = *(const float4*)&Wih[(size_t)(2 * HDIM + j) * 4];
    *(float4*)(c + 32768 + j * 4) = *(const float4*)&Wih[(size_t)(3 * HDIM + j) * 4];
    *(float4*)(c + 49152 + j * 4) = make_float4(bih[j] + bhh[j],
                                      bih[2 * HDIM + j] + bhh[2 * HDIM + j],
                                      bih[3 * HDIM + j] + bhh[3 * HDIM + j], 0.f);
    *(float4*)(c + 65536 + j * 4) = make_float4(Whr[j], Whr[HDIM + j], Whr[2 * HDIM + j], Whr[3 * HDIM + j]);
  } else if (i < 446464) {                // bp: small-layer MFMA B-frags
    int f = i - 348160;                   // 98304 threads, one 16B frag each
    int lane = f & 63;
    int tg = f >> 6;                      // (L*3+g)*256 + tile, 0..1535
    int L = tg / 768;
    int r2 = tg - L * 768;
    int g = r2 >> 8, tile = r2 & 255;
    const float* Wih = (L == 0) ? Wih1 : Wih2;
    const float* bih = (L == 0) ? bih1 : bih2;
    const float* bhh = (L == 0) ? bhh1 : bhh2;
    int q = lane >> 4, n = lane & 15;
    int j = tile * 16 + n;
    int go = (g == 0) ? 0 : (g + 1) * HDIM;    // PyTorch gate rows i,g,o
    u16 v[8] = {0, 0, 0, 0, 0, 0, 0, 0};
    if (q < 2) {
#pragma unroll
      for (int e = 0; e < 8; ++e) {
        float wv = Wih[(size_t)(go + j) * 4 + (e & 3)];
        u16 h, l;
        hilo(wv, h, l);
        v[e] = (q == 0) ? h : l;
      }
    } else if (q == 2) {
      float bv = bih[go + j] + bhh[go + j];
      hilo(bv, v[0], v[1]);
    }
    u16* bpp = (u16*)(ws + WS_BP);
    // r21: gate-contiguous layout [L][tile][gate][lane][8]
    size_t f2 = (((size_t)L * 256 + tile) * 3 + g) * 64 + lane;
    *(short8*)&bpp[f2 * 8] =
        (short8){(short)v[0], (short)v[1], (short)v[2], (short)v[3],
                 (short)v[4], (short)v[5], (short)v[6], (short)v[7]};
  }
}

// Layer 0 v2 (r17/r21 structure) + r25 XCD-AWARE BLOCK PERMUTATION.
// Counter evidence: FETCH_SIZE ~20MB/dispatch vs ~5.5MB unique (W panels
// re-fetched by ~8 XCDs because same-jb blocks sit at stride-64 indices ->
// round-robin scatters them). Permute so the 32 t-blocks sharing one W panel
// all land at indices == same (mod 8) -> same XCD -> ~1x panel fetch:
//   xs = b&7 (XCD slot), wi = b>>3, jb = xs*8 + (wi>>5), tbb = wi&31.
// Bijective on [0,2048); pp indexed explicitly by (jb,t) -> bit-identical.
__global__ __launch_bounds__(256, 3)
void lstm_layer0_mfma(const u16* __restrict__ xhi, const u16* __restrict__ xlo,
                      const u16* __restrict__ whi, const u16* __restrict__ wlo,
                      const float* __restrict__ bsc, const float* __restrict__ Whr,
                      float* __restrict__ pp) {
  __shared__ __align__(16) char smem[49152];
  u16* lw_hi = (u16*)smem;                 // [192 rows = g*64+j][64 k] swizzled
  u16* lw_lo = (u16*)(smem + 24576);

  const int tid = threadIdx.x;
  const int w = tid >> 6, lane = tid & 63;
  const int m = lane & 15, q = lane >> 4;
  const int b = blockIdx.x;
  const int xs = b & 7;                    // XCD slot under round-robin
  const int wi = b >> 3;                   // 0..255 within slot
  const int jb = xs * 8 + (wi >> 5);       // 8 W-panels per XCD slot
  const int tbb = wi & 31;
  const int j0 = jb * 64;
  const int t0 = tbb * 256;

  const int r8_ = lane >> 3;
  const int swo = ((lane & 7) ^ r8_) * 8;

  // ---- stage W (48 x 1KB units); 12 units/wave
#pragma unroll
  for (int ui = 0; ui < 12; ++ui) {
    const int u = w * 12 + ui;
    const u16* g;
    if (u < 24) {
      g = whi + (size_t)((u >> 3) * HDIM + j0 + (u & 7) * 8 + r8_) * 64 + swo;
    } else {
      const int uu = u - 24;
      g = wlo + (size_t)((uu >> 3) * HDIM + j0 + (uu & 7) * 8 + r8_) * 64 + swo;
    }
    gload16(g, smem + u * 1024);
  }

  // per-lane constants reused by both tiles (fly under the DMA)
  float whr_v[4][4];
#pragma unroll
  for (int p = 0; p < 4; ++p)
#pragma unroll
    for (int js = 0; js < 4; ++js)
      whr_v[p][js] = Whr[(size_t)p * HDIM + j0 + js * 16 + m];
  float biv[4], bgv[4], bov[4];
#pragma unroll
  for (int js = 0; js < 4; ++js) {
    const int j = j0 + js * 16 + m;
    biv[js] = bsc[j];
    bgv[js] = bsc[HDIM + j];
    bov[js] = bsc[2 * HDIM + j];
  }

  f32x4 acc[2][4][3];
  short8 al[2][2];

  auto zero_acc = [&]() {
#pragma unroll
    for (int ts = 0; ts < 2; ++ts)
#pragma unroll
      for (int js = 0; js < 4; ++js)
#pragma unroll
        for (int g = 0; g < 3; ++g) acc[ts][js][g] = (f32x4){0.f, 0.f, 0.f, 0.f};
  };
  auto load_al = [&](int tt) {
#pragma unroll
    for (int kc = 0; kc < 2; ++kc)
#pragma unroll
      for (int ts = 0; ts < 2; ++ts)
        al[kc][ts] = *(const short8*)&xlo[(size_t)(t0 + tt * 128 + w * 32 + ts * 16 + m) * KDIM + kc * 32 + q * 8];
  };
  auto compute = [&](int tt) {
#pragma unroll
    for (int kc = 0; kc < 2; ++kc) {
      short8 ah[2];
#pragma unroll
      for (int ts = 0; ts < 2; ++ts)
        ah[ts] = *(const short8*)&xhi[(size_t)(t0 + tt * 128 + w * 32 + ts * 16 + m) * KDIM + kc * 32 + q * 8];
      const int cs = ((kc * 4 + q) ^ (m & 7)) * 8;
#pragma unroll
      for (int js = 0; js < 4; ++js) {
#pragma unroll
        for (int g = 0; g < 3; ++g) {
          const int roff = (g * 64 + js * 16 + m) * 64 + cs;
          short8 bh = *(const short8*)&lw_hi[roff];
          short8 bl = *(const short8*)&lw_lo[roff];
#pragma unroll
          for (int ts = 0; ts < 2; ++ts) {
            acc[ts][js][g] = __builtin_amdgcn_mfma_f32_16x16x32_bf16(ah[ts], bh, acc[ts][js][g], 0, 0, 0);
            acc[ts][js][g] = __builtin_amdgcn_mfma_f32_16x16x32_bf16(al[kc][ts], bh, acc[ts][js][g], 0, 0, 0);
            acc[ts][js][g] = __builtin_amdgcn_mfma_f32_16x16x32_bf16(ah[ts], bl, acc[ts][js][g], 0, 0, 0);
          }
        }
      }
    }
  };
  auto act_proj = [&](int tt) {
    float hreg[2][4][4];
#pragma unroll
    for (int js = 0; js < 4; ++js) {
#pragma unroll
      for (int ts = 0; ts < 2; ++ts) {
#pragma unroll
        for (int r = 0; r < 4; ++r) {
          float ea = EXP2(acc[ts][js][0][r] + biv[js]);       // e^-i
          float eb = EXP2(acc[ts][js][1][r] + bgv[js]);       // e^-2g
          float c = (1.0f - eb) * rcpf((1.0f + ea) * (1.0f + eb));  // sig(i)tanh(g)
          float ec = EXP2(acc[ts][js][2][r] + bov[js]);       // e^-o
          hreg[ts][js][r] = h_merge(c, ec);                   // tanh(c)sig(o)
        }
      }
    }
    // projection partial over this lane's 4 js, then butterfly over 16 m-lanes
#pragma unroll
    for (int ts = 0; ts < 2; ++ts) {
#pragma unroll
      for (int r = 0; r < 4; ++r) {
        float pv[4];
#pragma unroll
        for (int p = 0; p < 4; ++p) {
          float s = 0.f;
#pragma unroll
          for (int js = 0; js < 4; ++js) s = fmaf(hreg[ts][js][r], whr_v[p][js], s);
#pragma unroll
          for (int ofs = 1; ofs < 16; ofs <<= 1) s += __shfl_xor(s, ofs, 16);
          pv[p] = s;
        }
        if (m == 0) {
          const int t = t0 + tt * 128 + w * 32 + ts * 16 + q * 4 + r;
          *(float4*)&pp[((size_t)jb * TSTEPS + t) * PDIM] = make_float4(pv[0], pv[1], pv[2], pv[3]);
        }
      }
    }
  };

  // ---- tile 0
  load_al(0);
  zero_acc();
  __syncthreads();                 // drain W DMA (only barrier in the kernel)
  compute(0);
  load_al(1);
  act_proj(0);
  zero_acc();
  compute(1);
  act_proj(1);
}

// FUSED post-L0 (r21, kept): ONE launch, 512 blocks x 512 threads, 16 t/blk.
// Gate-contiguous bp: one base pointer, imm offsets 0/1024/2048B, 3072B bump.
__global__ __launch_bounds__(512, 4)
void fused2(const float* __restrict__ pp, const u16* __restrict__ bp,
            const float* __restrict__ cwr1, const float* __restrict__ cwr2,
            float* __restrict__ out) {
  __shared__ __align__(16) float ytile[64];   // y[16 t][4 p] current layer input
  __shared__ float part[512];
  const int tid = threadIdx.x;
  const int lane = tid & 63, w = tid >> 6;    // w 0..7 = j-eighth
  const int n = lane & 15, qq = lane >> 4;
  const int t0 = blockIdx.x * 16;
  const f32x4 zc = (f32x4){0.f, 0.f, 0.f, 0.f};

  // ---- phase 0: reduce pp's 64 j-slices for this block's 16 t (bit-identical
  // to y0_reduce: 4 groups of serial-16, then left 4-chain).
  if (tid < 256) {
    const int o = tid & 63, sg = tid >> 6;
    float s = 0.f;
#pragma unroll 4
    for (int k = sg * 16; k < sg * 16 + 16; ++k)
      s += pp[(size_t)k * (TSTEPS * PDIM) + t0 * PDIM + o];
    part[sg * 64 + o] = s;
  }
  __syncthreads();
  if (tid < 64) ytile[tid] = ((part[tid] + part[64 + tid]) + part[128 + tid]) + part[192 + tid];
  __syncthreads();

#pragma unroll
  for (int L = 0; L < 2; ++L) {
    const u16* bL = bp + (size_t)L * 393216;
    const float4* cwr = (const float4*)((L == 0) ? cwr1 : cwr2);

    // A fragment: lane row m = n holds y[t0+n]; K-slots per prep scheme
    float4 yv = *(const float4*)&ytile[n * 4];
    float ye[4] = {yv.x, yv.y, yv.z, yv.w};
    u16 yh[4], yl[4];
#pragma unroll
    for (int e = 0; e < 4; ++e) hilo(ye[e], yh[e], yl[e]);
    short8 af = (short8){0, 0, 0, 0, 0, 0, 0, 0};
    if (qq < 2) {
      af[0] = (short)yh[0]; af[1] = (short)yh[1]; af[2] = (short)yh[2]; af[3] = (short)yh[3];
      af[4] = (short)yl[0]; af[5] = (short)yl[1]; af[6] = (short)yl[2]; af[7] = (short)yl[3];
    } else if (qq == 2) {
      af[0] = (short)0x3F80;                  // 1.0 at k16 (b_hi), k17 (b_lo)
      af[1] = (short)0x3F80;
    }

    float o_[4][4];
#pragma unroll
    for (int r = 0; r < 4; ++r)
#pragma unroll
      for (int p = 0; p < 4; ++p) o_[r][p] = 0.f;

    // one base pointer per wave-lane: tile = w*32+jt; u16 stride/tile = 1536
    const u16* bptr = bL + (size_t)(w * 32) * 1536 + (size_t)lane * 8;
    const float4* wptr = cwr + (size_t)(w * 32) * 16 + n;
#pragma unroll 4
    for (int jt = 0; jt < 32; ++jt) {
      short8 bfi = *(const short8*)(bptr);          // gate i: +0B
      short8 bfg = *(const short8*)(bptr + 512);    // gate g: +1024B
      short8 bfo = *(const short8*)(bptr + 1024);   // gate o: +2048B
      float4 wr = *wptr;                            // Whr[0..3][j], j=tile*16+n
      f32x4 ai = __builtin_amdgcn_mfma_f32_16x16x32_bf16(af, bfi, zc, 0, 0, 0);
      f32x4 ag = __builtin_amdgcn_mfma_f32_16x16x32_bf16(af, bfg, zc, 0, 0, 0);
      f32x4 ao = __builtin_amdgcn_mfma_f32_16x16x32_bf16(af, bfo, zc, 0, 0, 0);
#pragma unroll
      for (int r = 0; r < 4; ++r) {            // C-layout: col j = n, row t = qq*4+r
        float cc = sig_poly(ai[r]) * tanh_poly(ag[r]);
        float h = tanh_poly(cc) * sig_poly(ao[r]);
        o_[r][0] = fmaf(h, wr.x, o_[r][0]);
        o_[r][1] = fmaf(h, wr.y, o_[r][1]);
        o_[r][2] = fmaf(h, wr.z, o_[r][2]);
        o_[r][3] = fmaf(h, wr.w, o_[r][3]);
      }
      bptr += 1536;
      wptr += 16;
    }

    // reduce over the 16 j-lanes
#pragma unroll
    for (int r = 0; r < 4; ++r)
#pragma unroll
      for (int p = 0; p < 4; ++p) {
#pragma unroll
        for (int ofs = 1; ofs < 16; ofs <<= 1)
          o_[r][p] += __shfl_xor(o_[r][p], ofs, 16);
      }
    __syncthreads();                           // part free for reuse
    if (n == 0) {
#pragma unroll
      for (int r = 0; r < 4; ++r)
#pragma unroll
        for (int p = 0; p < 4; ++p)
          part[w * 64 + (qq * 4 + r) * 4 + p] = o_[r][p];
    }
    __syncthreads();
    if (tid < 64) {
      float s = part[tid];
#pragma unroll
      for (int w2 = 1; w2 < 8; ++w2) s += part[w2 * 64 + tid];
      ytile[tid] = s;
    }
    __syncthreads();
  }

  // ---- final out: 64 consecutive floats per block, coalesced
  if (tid < 64) out[t0 * PDIM + tid] = ytile[tid];
}

extern "C" void kernel_launch(void* const* d_in, const int* in_sizes, int n_in,
                              void* d_out, int out_size, void* d_ws, size_t ws_size,
                              hipStream_t stream) {
  const float* x    = (const float*)d_in[0];
  const float* Wih0 = (const float*)d_in[1];
  const float* bih0 = (const float*)d_in[3];
  const float* bhh0 = (const float*)d_in[4];
  const float* Whr0 = (const float*)d_in[5];
  const float* Wih1 = (const float*)d_in[6];
  const float* bih1 = (const float*)d_in[8];
  const float* bhh1 = (const float*)d_in[9];
  const float* Whr1 = (const float*)d_in[10];
  const float* Wih2 = (const float*)d_in[11];
  const float* bih2 = (const float*)d_in[13];
  const float* bhh2 = (const float*)d_in[14];
  const float* Whr2 = (const float*)d_in[15];
  float* out = (float*)d_out;
  float* ws = (float*)d_ws;
  float* pp = ws + WS_PP;
  const u16* bp = (const u16*)(ws + WS_BP);

  prep_kernel<<<dim3(1744), dim3(256), 0, stream>>>(
      x, Wih0, bih0, bhh0, Wih1, bih1, bhh1, Whr1, Wih2, bih2, bhh2, Whr2, ws);

  lstm_layer0_mfma<<<dim3(2048), dim3(256), 0, stream>>>(
      (const u16*)(ws + WS_XHI), (const u16*)(ws + WS_XLO),
      (const u16*)(ws + WS_WHI), (const u16*)(ws + WS_WLO),
      ws + WS_BSC, Whr0, pp);

  fused2<<<dim3(512), dim3(512), 0, stream>>>(
      pp, bp, ws + WS_C1 + 65536, ws + WS_C2 + 65536, out);
}

// Round 16
// 198.679 us; speedup vs baseline: 3.1655x; 1.0159x over previous
//
#include <hip/hip_runtime.h>

#define TSTEPS 8192
#define HDIM 4096
#define PDIM 4
#define KDIM 64

typedef unsigned short u16;
typedef __attribute__((ext_vector_type(8))) short short8;
typedef __attribute__((ext_vector_type(4))) float f32x4;

#define S1 -1.44269504089f   // -log2(e)
#define S2 -2.88539008177f   // -2*log2(e)

#if __has_builtin(__builtin_amdgcn_exp2f)
#define EXP2(x) __builtin_amdgcn_exp2f(x)
#else
#define EXP2(x) exp2f(x)
#endif
__device__ __forceinline__ float rcpf(float x) { return __builtin_amdgcn_rcpf(x); }

// tanh(c)*sig(o) for c in (-1,1), given ec = e^-o. Pade CF-7 tanh (err ~5e-6)
// merged into sig's rcp (r10 form -- best measured for L0 epilogue).
__device__ __forceinline__ float h_merge(float c, float ec) {
  float c2 = c * c;
  float num = c * fmaf(c2, 10.0f, 105.0f);
  float den = fmaf(c2, 45.0f, 105.0f) + c2 * c2;
  return num * rcpf(den * (1.0f + ec));
}

// Polynomial sig/tanh for SMALL-LAYER gates only (|z| <= ~0.6, 5-sigma; poly
// valid to |z|~1 at ~2e-5 err).
__device__ __forceinline__ float sig_poly(float z) {
  float z2 = z * z;
  float q = fmaf(z2, -2.1081349e-4f, 2.0833333e-3f);   // -17/80640, 1/480
  q = fmaf(z2, q, -2.0833333e-2f);                     // -1/48
  q = fmaf(z2, q, 0.25f);                              // 1/4
  return fmaf(z, q, 0.5f);
}
__device__ __forceinline__ float tanh_poly(float z) {
  float z2 = z * z;
  float q = fmaf(z2, -5.3968254e-2f, 1.3333333e-1f);   // -17/315, 2/15
  q = fmaf(z2, q, -3.3333333e-1f);                     // -1/3
  q = fmaf(z2, q, 1.0f);
  return z * q;
}

// async global->LDS DMA, 16B per lane; LDS dest = uniform base + lane*16
__device__ __forceinline__ void gload16(const void* g, void* l) {
  __builtin_amdgcn_global_load_lds((const __attribute__((address_space(1))) unsigned int*)g,
                                   (__attribute__((address_space(3))) unsigned int*)l,
                                   16, 0, 0);
}

__device__ __forceinline__ u16 bf16_rne(float f) {
  unsigned u = __float_as_uint(f);
  u += 0x7FFF + ((u >> 16) & 1);
  return (u16)(u >> 16);
}
__device__ __forceinline__ void hilo(float v, u16& h, u16& l) {
  h = bf16_rne(v);
  l = bf16_rne(v - __uint_as_float((unsigned)h << 16));
}

// ---- workspace layout (float offsets) ----
#define WS_Y0   0
#define WS_Y1   32768
#define WS_BSC  65536
#define WS_C1   77824
#define WS_C2   159744
#define WS_XHI  241664
#define WS_XLO  503808
#define WS_WHI  765952
#define WS_WLO  1159168
#define WS_PP   1552384
#define WS_BP   3649536
// bp (r21 layout, GATE-CONTIGUOUS): [L][tile][gate][lane][8 u16].

// One-shot prep (single launch; r23 probe measured its warm cost at ~1-2us).
__global__ void prep_kernel(const float* __restrict__ x,
                            const float* __restrict__ Wih0, const float* __restrict__ bih0,
                            const float* __restrict__ bhh0,
                            const float* __restrict__ Wih1, const float* __restrict__ bih1,
                            const float* __restrict__ bhh1, const float* __restrict__ Whr1,
                            const float* __restrict__ Wih2, const float* __restrict__ bih2,
                            const float* __restrict__ bhh2, const float* __restrict__ Whr2,
                            float* __restrict__ ws) {
  const int i = blockIdx.x * 256 + threadIdx.x;
  u16* xhi = (u16*)(ws + WS_XHI);
  u16* xlo = (u16*)(ws + WS_XLO);
  u16* whi = (u16*)(ws + WS_WHI);
  u16* wlo = (u16*)(ws + WS_WLO);

  if (i < 131072) {                       // x: 131072 float4 units, unscaled
    float4 v = *(const float4*)&x[i * 4];
    float val[4] = {v.x, v.y, v.z, v.w};
    u16 h[4], l[4];
#pragma unroll
    for (int e = 0; e < 4; ++e) hilo(val[e], h[e], l[e]);
    *(ushort4*)&xhi[i * 4] = make_ushort4(h[0], h[1], h[2], h[3]);
    *(ushort4*)&xlo[i * 4] = make_ushort4(l[0], l[1], l[2], l[3]);
  } else if (i < 327680) {                // W_ih0: 196608 float4 units, scaled
    int f = i - 131072;
    int el4 = f * 4;
    int r = el4 >> 6;                     // packed row 0..12287 ([gate][j])
    int k4 = el4 & 63;
    int gate = r >> 12, jr = r & 4095;
    int src = (gate == 0) ? jr : (gate + 1) * HDIM + jr;   // i,g,o = rows 0,2H,3H
    float sc = (gate == 1) ? S2 : S1;
    float4 v = *(const float4*)&Wih0[(size_t)src * KDIM + k4];
    float val[4] = {sc * v.x, sc * v.y, sc * v.z, sc * v.w};
    u16 h[4], l[4];
#pragma unroll
    for (int e = 0; e < 4; ++e) hilo(val[e], h[e], l[e]);
    *(ushort4*)&whi[r * KDIM + k4] = make_ushort4(h[0], h[1], h[2], h[3]);
    *(ushort4*)&wlo[r * KDIM + k4] = make_ushort4(l[0], l[1], l[2], l[3]);
  } else if (i < 339968) {                // bsc[3][4096], scaled merged bias (L0)
    int f = i - 327680;
    int g = f >> 12, j = f & 4095;
    int src = (g == 0) ? j : (g + 1) * HDIM + j;
    float sc = (g == 1) ? S2 : S1;
    ws[WS_BSC + f] = sc * (bih0[src] + bhh0[src]);
  } else if (i < 348160) {                // c1/c2 SoA records (wr block consumed)
    int f = i - 339968;
    const float* Wih = (f < 4096) ? Wih1 : Wih2;
    const float* bih = (f < 4096) ? bih1 : bih2;
    const float* bhh = (f < 4096) ? bhh1 : bhh2;
    const float* Whr = (f < 4096) ? Whr1 : Whr2;
    float* c = ws + ((f < 4096) ? WS_C1 : WS_C2);
    int j = f & 4095;
    *(float4*)(c + j * 4)         = *(const float4*)&Wih[(size_t)j * 4];
    *(float4*)(c + 16384 + j * 4) = *(const float4*)&Wih[(size_t)(2 * HDIM + j) * 4];
    *(float4*)(c + 32768 + j * 4) = *(const float4*)&Wih[(size_t)(3 * HDIM + j) * 4];
    *(float4*)(c + 49152 + j * 4) = make_float4(bih[j] + bhh[j],
                                      bih[2 * HDIM + j] + bhh[2 * HDIM + j],
                                      bih[3 * HDIM + j] + bhh[3 * HDIM + j], 0.f);
    *(float4*)(c + 65536 + j * 4) = make_float4(Whr[j], Whr[HDIM + j], Whr[2 * HDIM + j], Whr[3 * HDIM + j]);
  } else if (i < 446464) {                // bp: small-layer MFMA B-frags
    int f = i - 348160;                   // 98304 threads, one 16B frag each
    int lane = f & 63;
    int tg = f >> 6;                      // (L*3+g)*256 + tile, 0..1535
    int L = tg / 768;
    int r2 = tg - L * 768;
    int g = r2 >> 8, tile = r2 & 255;
    const float* Wih = (L == 0) ? Wih1 : Wih2;
    const float* bih = (L == 0) ? bih1 : bih2;
    const float* bhh = (L == 0) ? bhh1 : bhh2;
    int q = lane >> 4, n = lane & 15;
    int j = tile * 16 + n;
    int go = (g == 0) ? 0 : (g + 1) * HDIM;    // PyTorch gate rows i,g,o
    u16 v[8] = {0, 0, 0, 0, 0, 0, 0, 0};
    if (q < 2) {
#pragma unroll
      for (int e = 0; e < 8; ++e) {
        float wv = Wih[(size_t)(go + j) * 4 + (e & 3)];
        u16 h, l;
        hilo(wv, h, l);
        v[e] = (q == 0) ? h : l;
      }
    } else if (q == 2) {
      float bv = bih[go + j] + bhh[go + j];
      hilo(bv, v[0], v[1]);
    }
    u16* bpp = (u16*)(ws + WS_BP);
    // r21: gate-contiguous layout [L][tile][gate][lane][8]
    size_t f2 = (((size_t)L * 256 + tile) * 3 + g) * 64 + lane;
    *(short8*)&bpp[f2 * 8] =
        (short8){(short)v[0], (short)v[1], (short)v[2], (short)v[3],
                 (short)v[4], (short)v[5], (short)v[6], (short)v[7]};
  }
}

// Layer 0 (r26): r17/r21 structure + r25 XCD swizzle (WRITE 56.7->38.3MB,
// -3.6us, verified) + SINGLE-TILE blocks. The two-tile loop becomes two
// blocks (grid 2048->4096, 128t each): halves T_block (27->13us) so the
// final-wave drain idles CUs for half as long (2048 over 768 resident =
// 2.67 rounds; drain loss scales with T_block). Per-element math, order,
// and pp indexing unchanged -> bit-identical output.
__global__ __launch_bounds__(256, 3)
void lstm_layer0_mfma(const u16* __restrict__ xhi, const u16* __restrict__ xlo,
                      const u16* __restrict__ whi, const u16* __restrict__ wlo,
                      const float* __restrict__ bsc, const float* __restrict__ Whr,
                      float* __restrict__ pp) {
  __shared__ __align__(16) char smem[49152];
  u16* lw_hi = (u16*)smem;                 // [192 rows = g*64+j][64 k] swizzled
  u16* lw_lo = (u16*)(smem + 24576);

  const int tid = threadIdx.x;
  const int w = tid >> 6, lane = tid & 63;
  const int m = lane & 15, q = lane >> 4;
  const int b = blockIdx.x;
  const int xs = b & 7;                    // XCD slot under round-robin
  const int wi = b >> 3;                   // 0..511 within slot
  const int jb = xs * 8 + (wi >> 6);       // 8 W-panels per XCD slot
  const int tbb = wi & 63;                 // 64 t-blocks of 128 per panel
  const int j0 = jb * 64;
  const int t0 = tbb * 128;

  const int r8_ = lane >> 3;
  const int swo = ((lane & 7) ^ r8_) * 8;

  // ---- stage W (48 x 1KB units); 12 units/wave
#pragma unroll
  for (int ui = 0; ui < 12; ++ui) {
    const int u = w * 12 + ui;
    const u16* g;
    if (u < 24) {
      g = whi + (size_t)((u >> 3) * HDIM + j0 + (u & 7) * 8 + r8_) * 64 + swo;
    } else {
      const int uu = u - 24;
      g = wlo + (size_t)((uu >> 3) * HDIM + j0 + (uu & 7) * 8 + r8_) * 64 + swo;
    }
    gload16(g, smem + u * 1024);
  }

  // per-lane constants (fly under the DMA)
  float whr_v[4][4];
#pragma unroll
  for (int p = 0; p < 4; ++p)
#pragma unroll
    for (int js = 0; js < 4; ++js)
      whr_v[p][js] = Whr[(size_t)p * HDIM + j0 + js * 16 + m];
  float biv[4], bgv[4], bov[4];
#pragma unroll
  for (int js = 0; js < 4; ++js) {
    const int j = j0 + js * 16 + m;
    biv[js] = bsc[j];
    bgv[js] = bsc[HDIM + j];
    bov[js] = bsc[2 * HDIM + j];
  }

  f32x4 acc[2][4][3];
  short8 al[2][2];

  // ---- single 128-t tile
#pragma unroll
  for (int kc = 0; kc < 2; ++kc)
#pragma unroll
    for (int ts = 0; ts < 2; ++ts)
      al[kc][ts] = *(const short8*)&xlo[(size_t)(t0 + w * 32 + ts * 16 + m) * KDIM + kc * 32 + q * 8];
#pragma unroll
  for (int ts = 0; ts < 2; ++ts)
#pragma unroll
    for (int js = 0; js < 4; ++js)
#pragma unroll
      for (int g = 0; g < 3; ++g) acc[ts][js][g] = (f32x4){0.f, 0.f, 0.f, 0.f};

  __syncthreads();                 // drain W DMA (only barrier in the kernel)

#pragma unroll
  for (int kc = 0; kc < 2; ++kc) {
    short8 ah[2];
#pragma unroll
    for (int ts = 0; ts < 2; ++ts)
      ah[ts] = *(const short8*)&xhi[(size_t)(t0 + w * 32 + ts * 16 + m) * KDIM + kc * 32 + q * 8];
    const int cs = ((kc * 4 + q) ^ (m & 7)) * 8;
#pragma unroll
    for (int js = 0; js < 4; ++js) {
#pragma unroll
      for (int g = 0; g < 3; ++g) {
        const int roff = (g * 64 + js * 16 + m) * 64 + cs;
        short8 bh = *(const short8*)&lw_hi[roff];
        short8 bl = *(const short8*)&lw_lo[roff];
#pragma unroll
        for (int ts = 0; ts < 2; ++ts) {
          acc[ts][js][g] = __builtin_amdgcn_mfma_f32_16x16x32_bf16(ah[ts], bh, acc[ts][js][g], 0, 0, 0);
          acc[ts][js][g] = __builtin_amdgcn_mfma_f32_16x16x32_bf16(al[kc][ts], bh, acc[ts][js][g], 0, 0, 0);
          acc[ts][js][g] = __builtin_amdgcn_mfma_f32_16x16x32_bf16(ah[ts], bl, acc[ts][js][g], 0, 0, 0);
        }
      }
    }
  }

  // ---- epilogue: activations + projection + butterfly
  {
    float hreg[2][4][4];
#pragma unroll
    for (int js = 0; js < 4; ++js) {
#pragma unroll
      for (int ts = 0; ts < 2; ++ts) {
#pragma unroll
        for (int r = 0; r < 4; ++r) {
          float ea = EXP2(acc[ts][js][0][r] + biv[js]);       // e^-i
          float eb = EXP2(acc[ts][js][1][r] + bgv[js]);       // e^-2g
          float c = (1.0f - eb) * rcpf((1.0f + ea) * (1.0f + eb));  // sig(i)tanh(g)
          float ec = EXP2(acc[ts][js][2][r] + bov[js]);       // e^-o
          hreg[ts][js][r] = h_merge(c, ec);                   // tanh(c)sig(o)
        }
      }
    }
#pragma unroll
    for (int ts = 0; ts < 2; ++ts) {
#pragma unroll
      for (int r = 0; r < 4; ++r) {
        float pv[4];
#pragma unroll
        for (int p = 0; p < 4; ++p) {
          float s = 0.f;
#pragma unroll
          for (int js = 0; js < 4; ++js) s = fmaf(hreg[ts][js][r], whr_v[p][js], s);
#pragma unroll
          for (int ofs = 1; ofs < 16; ofs <<= 1) s += __shfl_xor(s, ofs, 16);
          pv[p] = s;
        }
        if (m == 0) {
          const int t = t0 + w * 32 + ts * 16 + q * 4 + r;
          *(float4*)&pp[((size_t)jb * TSTEPS + t) * PDIM] = make_float4(pv[0], pv[1], pv[2], pv[3]);
        }
      }
    }
  }
}

// FUSED post-L0 (r21, kept): ONE launch, 512 blocks x 512 threads, 16 t/blk.
// Gate-contiguous bp: one base pointer, imm offsets 0/1024/2048B, 3072B bump.
__global__ __launch_bounds__(512, 4)
void fused2(const float* __restrict__ pp, const u16* __restrict__ bp,
            const float* __restrict__ cwr1, const float* __restrict__ cwr2,
            float* __restrict__ out) {
  __shared__ __align__(16) float ytile[64];   // y[16 t][4 p] current layer input
  __shared__ float part[512];
  const int tid = threadIdx.x;
  const int lane = tid & 63, w = tid >> 6;    // w 0..7 = j-eighth
  const int n = lane & 15, qq = lane >> 4;
  const int t0 = blockIdx.x * 16;
  const f32x4 zc = (f32x4){0.f, 0.f, 0.f, 0.f};

  // ---- phase 0: reduce pp's 64 j-slices for this block's 16 t (bit-identical
  // to y0_reduce: 4 groups of serial-16, then left 4-chain).
  if (tid < 256) {
    const int o = tid & 63, sg = tid >> 6;
    float s = 0.f;
#pragma unroll 4
    for (int k = sg * 16; k < sg * 16 + 16; ++k)
      s += pp[(size_t)k * (TSTEPS * PDIM) + t0 * PDIM + o];
    part[sg * 64 + o] = s;
  }
  __syncthreads();
  if (tid < 64) ytile[tid] = ((part[tid] + part[64 + tid]) + part[128 + tid]) + part[192 + tid];
  __syncthreads();

#pragma unroll
  for (int L = 0; L < 2; ++L) {
    const u16* bL = bp + (size_t)L * 393216;
    const float4* cwr = (const float4*)((L == 0) ? cwr1 : cwr2);

    // A fragment: lane row m = n holds y[t0+n]; K-slots per prep scheme
    float4 yv = *(const float4*)&ytile[n * 4];
    float ye[4] = {yv.x, yv.y, yv.z, yv.w};
    u16 yh[4], yl[4];
#pragma unroll
    for (int e = 0; e < 4; ++e) hilo(ye[e], yh[e], yl[e]);
    short8 af = (short8){0, 0, 0, 0, 0, 0, 0, 0};
    if (qq < 2) {
      af[0] = (short)yh[0]; af[1] = (short)yh[1]; af[2] = (short)yh[2]; af[3] = (short)yh[3];
      af[4] = (short)yl[0]; af[5] = (short)yl[1]; af[6] = (short)yl[2]; af[7] = (short)yl[3];
    } else if (qq == 2) {
      af[0] = (short)0x3F80;                  // 1.0 at k16 (b_hi), k17 (b_lo)
      af[1] = (short)0x3F80;
    }

    float o_[4][4];
#pragma unroll
    for (int r = 0; r < 4; ++r)
#pragma unroll
      for (int p = 0; p < 4; ++p) o_[r][p] = 0.f;

    // one base pointer per wave-lane: tile = w*32+jt; u16 stride/tile = 1536
    const u16* bptr = bL + (size_t)(w * 32) * 1536 + (size_t)lane * 8;
    const float4* wptr = cwr + (size_t)(w * 32) * 16 + n;
#pragma unroll 4
    for (int jt = 0; jt < 32; ++jt) {
      short8 bfi = *(const short8*)(bptr);          // gate i: +0B
      short8 bfg = *(const short8*)(bptr + 512);    // gate g: +1024B
      short8 bfo = *(const short8*)(bptr + 1024);   // gate o: +2048B
      float4 wr = *wptr;                            // Whr[0..3][j], j=tile*16+n
      f32x4 ai = __builtin_amdgcn_mfma_f32_16x16x32_bf16(af, bfi, zc, 0, 0, 0);
      f32x4 ag = __builtin_amdgcn_mfma_f32_16x16x32_bf16(af, bfg, zc, 0, 0, 0);
      f32x4 ao = __builtin_amdgcn_mfma_f32_16x16x32_bf16(af, bfo, zc, 0, 0, 0);
#pragma unroll
      for (int r = 0; r < 4; ++r) {            // C-layout: col j = n, row t = qq*4+r
        float cc = sig_poly(ai[r]) * tanh_poly(ag[r]);
        float h = tanh_poly(cc) * sig_poly(ao[r]);
        o_[r][0] = fmaf(h, wr.x, o_[r][0]);
        o_[r][1] = fmaf(h, wr.y, o_[r][1]);
        o_[r][2] = fmaf(h, wr.z, o_[r][2]);
        o_[r][3] = fmaf(h, wr.w, o_[r][3]);
      }
      bptr += 1536;
      wptr += 16;
    }

    // reduce over the 16 j-lanes
#pragma unroll
    for (int r = 0; r < 4; ++r)
#pragma unroll
      for (int p = 0; p < 4; ++p) {
#pragma unroll
        for (int ofs = 1; ofs < 16; ofs <<= 1)
          o_[r][p] += __shfl_xor(o_[r][p], ofs, 16);
      }
    __syncthreads();                           // part free for reuse
    if (n == 0) {
#pragma unroll
      for (int r = 0; r < 4; ++r)
#pragma unroll
        for (int p = 0; p < 4; ++p)
          part[w * 64 + (qq * 4 + r) * 4 + p] = o_[r][p];
    }
    __syncthreads();
    if (tid < 64) {
      float s = part[tid];
#pragma unroll
      for (int w2 = 1; w2 < 8; ++w2) s += part[w2 * 64 + tid];
      ytile[tid] = s;
    }
    __syncthreads();
  }

  // ---- final out: 64 consecutive floats per block, coalesced
  if (tid < 64) out[t0 * PDIM + tid] = ytile[tid];
}

extern "C" void kernel_launch(void* const* d_in, const int* in_sizes, int n_in,
                              void* d_out, int out_size, void* d_ws, size_t ws_size,
                              hipStream_t stream) {
  const float* x    = (const float*)d_in[0];
  const float* Wih0 = (const float*)d_in[1];
  const float* bih0 = (const float*)d_in[3];
  const float* bhh0 = (const float*)d_in[4];
  const float* Whr0 = (const float*)d_in[5];
  const float* Wih1 = (const float*)d_in[6];
  const float* bih1 = (const float*)d_in[8];
  const float* bhh1 = (const float*)d_in[9];
  const float* Whr1 = (const float*)d_in[10];
  const float* Wih2 = (const float*)d_in[11];
  const float* bih2 = (const float*)d_in[13];
  const float* bhh2 = (const float*)d_in[14];
  const float* Whr2 = (const float*)d_in[15];
  float* out = (float*)d_out;
  float* ws = (float*)d_ws;
  float* pp = ws + WS_PP;
  const u16* bp = (const u16*)(ws + WS_BP);

  prep_kernel<<<dim3(1744), dim3(256), 0, stream>>>(
      x, Wih0, bih0, bhh0, Wih1, bih1, bhh1, Whr1, Wih2, bih2, bhh2, Whr2, ws);

  lstm_layer0_mfma<<<dim3(4096), dim3(256), 0, stream>>>(
      (const u16*)(ws + WS_XHI), (const u16*)(ws + WS_XLO),
      (const u16*)(ws + WS_WHI), (const u16*)(ws + WS_WLO),
      ws + WS_BSC, Whr0, pp);

  fused2<<<dim3(512), dim3(512), 0, stream>>>(
      pp, bp, ws + WS_C1 + 65536, ws + WS_C2 + 65536, out);
}